// Round 12
// baseline (358.067 us; speedup 1.0000x reference)
//
#include <hip/hip_runtime.h>

#define NROWS   262144
#define NCODES  1024
#define DIM     64
#define NTILES  64       // 16-code MFMA tiles covering 1024 codes
#define TILEB   2048     // bytes per tile in fragment layout (2 x 1024)
#define PADT    4        // prefetch overrun pad (tiles 64..67 read, never used)

typedef _Float16 half8 __attribute__((ext_vector_type(8)));
typedef __attribute__((ext_vector_type(4))) float f32x4;

#define MFMA16(acc, a, b) acc = __builtin_amdgcn_mfma_f32_16x16x32_f16(a, b, acc, 0, 0, 0)

// ---------------------------------------------------------------------------
// Prep: unchanged (validated arithmetic; R3 fragment layout; eslots E).
// ---------------------------------------------------------------------------
__global__ __launch_bounds__(256) void vq_prep(const float* __restrict__ cb,
                                               float* __restrict__ hcsq,
                                               char* __restrict__ stream,
                                               float* __restrict__ eslots) {
    const int k = blockIdx.x * 256 + threadIdx.x;   // 0..1023
    const float4* row = (const float4*)(cb + (size_t)k * DIM);
    char* base = stream + (size_t)(k >> 4) * TILEB + (size_t)(k & 15) * 16;
    float s = 0.f, r2 = 0.f;
#pragma unroll
    for (int i = 0; i < 8; ++i) {   // chunk i: halves i*8..i*8+7
        float4 a = row[2 * i], b = row[2 * i + 1];
        float v[8] = {a.x, a.y, a.z, a.w, b.x, b.y, b.z, b.w};
        union { half8 f; _Float16 e[8]; } uh;
#pragma unroll
        for (int j = 0; j < 8; ++j) {
            float c = v[j];
            s += c * c;                    // sequential chain (matches r4/r1)
            _Float16 h = (_Float16)c;      // RNE
            uh.e[j] = h;
            float d = c - (float)h;        // true residual
            r2 += d * d;
        }
        // chunk i -> j = i>>2 slot, q-position = i&3 (validated R3 layout)
        *(half8*)(base + ((i >> 2) << 10) + ((i & 3) << 8)) = uh.f;
    }
    hcsq[k] = 0.5f * s;
    float w = r2;
#pragma unroll
    for (int off = 1; off < 64; off <<= 1) w = fmaxf(w, __shfl_xor(w, off));
    if ((threadIdx.x & 63) == 0)
        eslots[blockIdx.x * 4 + (threadIdx.x >> 6)] = w;   // plain store
}

// ---------------------------------------------------------------------------
// Main. R3's 97-us loop body VERBATIM + block-pooled rescue. R11 rescue fix:
// the R7/R9/R10 tail (~22 us/row) was the wave's own serial chain -- 32
// iterations of {loads + 8 x 4-deep __shfl_xor chains}, and the shuffles ARE
// ds-pipe ops; TLP (R9) doesn't shorten a serial chain, and source-level
// staging (R10) was legally sunk by the allocator (VGPR stayed 64). R11
// removes cross-lane ops from the scan: lane L owns codes {L, L+64, ...},
// computes full 64-dim dots locally; partials are summed in the EXACT
// binary-tree order of the validated butterfly (fp add commutativity makes
// the old per-lane results bitwise equal to this tree), so s is bitwise
// identical to the validated rescue. One 6-step cross-lane top-1 butterfly
// per row (validated min-index tie-break) replaces 1024 ds-ops.
// ---------------------------------------------------------------------------
#define SELECT(aa, ab, tl)                                                        \
    {                                                                             \
        const int _tl = (tl);                                                     \
        _Pragma("unroll")                                                         \
        for (int r = 0; r < 4; ++r) {                                             \
            float s0 = (aa)[r];                                                   \
            bool g0 = s0 > best[0][r];                                            \
            second[0][r] = __builtin_amdgcn_fmed3f(s0, best[0][r], second[0][r]); \
            best[0][r] = g0 ? s0 : best[0][r];                                    \
            btile[0][r] = g0 ? _tl : btile[0][r];                                 \
            float s1 = (ab)[r];                                                   \
            bool g1 = s1 > best[1][r];                                            \
            second[1][r] = __builtin_amdgcn_fmed3f(s1, best[1][r], second[1][r]); \
            best[1][r] = g1 ? s1 : best[1][r];                                    \
            btile[1][r] = g1 ? _tl : btile[1][r];                                 \
        }                                                                         \
    }

#define PHASE(fA, fB, a0, a1, o0, o1, TT)                     \
    {                                                         \
        const int _T = (TT);                                  \
        float nh = nshc[_T * 16 + m];                         \
        SELECT(o0, o1, _T - 1);                               \
        a0 = (f32x4){nh, nh, nh, nh};                         \
        a1 = a0;                                              \
        MFMA16(a0, xh[0][0], fA); MFMA16(a1, xh[1][0], fA);   \
        MFMA16(a0, xh[0][1], fB); MFMA16(a1, xh[1][1], fB);   \
        MFMA16(a0, xl[0][0], fA); MFMA16(a1, xl[1][0], fA);   \
        MFMA16(a0, xl[0][1], fB); MFMA16(a1, xl[1][1], fB);   \
        fA = *(const half8*)(gpre);                           \
        fB = *(const half8*)(gpre + 1024);                    \
        gpre += TILEB;                                        \
    }

#define DOT4(xx, cc) ((xx).x * (cc).x + (xx).y * (cc).y + (xx).z * (cc).z + (xx).w * (cc).w)

__global__ __launch_bounds__(256, 4) void vq_main(const float* __restrict__ inputs,
                                                  const float* __restrict__ cb,
                                                  const float* __restrict__ hcsq,
                                                  const char* __restrict__ stream,
                                                  const float* __restrict__ eslots,
                                                  float* __restrict__ out) {
    __shared__ float nshc[NCODES];     // negated 0.5||c||^2 (4 KB, loaded once)
    __shared__ unsigned s_rows[128];   // block-pooled flagged rows
    __shared__ unsigned s_cnt;
    const int tid = threadIdx.x;
    const int lane = tid & 63;
    const int wave = tid >> 6;
    const int m = lane & 15;   // A row-in-tile / B code-in-tile / D col
    const int q = lane >> 4;   // k-quad
    const size_t rowbase = (size_t)blockIdx.x * 128 + (size_t)wave * 32;

    for (int i = tid; i < NCODES; i += 256) nshc[i] = -hcsq[i];
    if (tid == 0) s_cnt = 0u;

    float e2 = 0.f;
#pragma unroll
    for (int i = 0; i < 16; ++i) e2 = fmaxf(e2, eslots[i]);
    const float E = sqrtf(e2) * 1.001f;

    // A fragments (fp16 hi+lo of x) + exact row sum-of-squares for the margin.
    half8 xh[2][2], xl[2][2];
    float xsq[2];
#pragma unroll
    for (int t = 0; t < 2; ++t) {
        const float* px = inputs + (rowbase + t * 16 + m) * DIM;
        float acc = 0.f;
#pragma unroll
        for (int s = 0; s < 2; ++s) {
            const float4* p = (const float4*)(px + q * 8 + s * 32);
            float4 v0 = p[0], v1 = p[1];
            float v[8] = {v0.x, v0.y, v0.z, v0.w, v1.x, v1.y, v1.z, v1.w};
            union { half8 f; _Float16 e[8]; } uh, ul;
#pragma unroll
            for (int j = 0; j < 8; ++j) {
                acc += v[j] * v[j];
                _Float16 h = (_Float16)v[j];
                uh.e[j] = h;
                ul.e[j] = (_Float16)(v[j] - (float)h);
            }
            xh[t][s] = uh.f;
            xl[t][s] = ul.f;
        }
        acc += __shfl_xor(acc, 16);   // reduce across k-quads (same m)
        acc += __shfl_xor(acc, 32);
        xsq[t] = acc;
    }
    __syncthreads();   // nshc + s_cnt ready

    float best[2][4], second[2][4];
    int btile[2][4];
#pragma unroll
    for (int t = 0; t < 2; ++t)
#pragma unroll
        for (int r = 0; r < 4; ++r) {
            best[t][r] = -INFINITY;
            second[t][r] = -INFINITY;
            btile[t][r] = 0;
        }

    // 4-tile rotating register prefetch pipeline (R3-verbatim).
    const char* gL = stream + (size_t)lane * 16;
    half8 f0a = *(const half8*)(gL);
    half8 f0b = *(const half8*)(gL + 1024);
    half8 f1a = *(const half8*)(gL + TILEB);
    half8 f1b = *(const half8*)(gL + TILEB + 1024);
    half8 f2a = *(const half8*)(gL + 2 * TILEB);
    half8 f2b = *(const half8*)(gL + 2 * TILEB + 1024);
    half8 f3a = *(const half8*)(gL + 3 * TILEB);
    half8 f3b = *(const half8*)(gL + 3 * TILEB + 1024);
    const char* gpre = gL + 4 * TILEB;

    f32x4 accA0, accA1, accB0, accB1;
    accB0 = (f32x4){-INFINITY, -INFINITY, -INFINITY, -INFINITY};
    accB1 = accB0;

    for (int it = 0; it < 16; ++it) {
        const int T = it * 4;
        PHASE(f0a, f0b, accA0, accA1, accB0, accB1, T + 0);
        PHASE(f1a, f1b, accB0, accB1, accA0, accA1, T + 1);
        PHASE(f2a, f2b, accA0, accA1, accB0, accB1, T + 2);
        PHASE(f3a, f3b, accB0, accB1, accA0, accA1, T + 3);
    }
    SELECT(accB0, accB1, NTILES - 1);   // drain last pending tile

    // Top-2 merge; write non-flagged rows; pool flagged rows in LDS.
#pragma unroll
    for (int t = 0; t < 2; ++t)
#pragma unroll
        for (int r = 0; r < 4; ++r) {
            float b = best[t][r], sc = second[t][r];
            int bi = btile[t][r] * 16 + m;   // reconstruct code index
#pragma unroll
            for (int off = 1; off < 16; off <<= 1) {
                float ob = __shfl_xor(b, off);
                float os = __shfl_xor(sc, off);
                int oi = __shfl_xor(bi, off);
                sc = fmaxf(fmaxf(sc, os), fminf(b, ob));
                if (ob > b || (ob == b && oi < bi)) { b = ob; bi = oi; }
            }
            size_t row = rowbase + t * 16 + q * 4 + r;
            float xs = __shfl(xsq[t], (lane & 48) | (q * 4 + r));
            float marg = 2.0f * (sqrtf(xs) * E + 1e-3f);
            bool flg = (b - sc) < marg;   // group-uniform
            if (!flg) {
                const float4* src = (const float4*)(cb + (size_t)bi * DIM);
                ((float4*)(out + row * DIM))[m] = src[m];
            } else if (m == 0) {
                unsigned p = atomicAdd(&s_cnt, 1u);   // LDS atomic
                s_rows[p] = (unsigned)row;            // p < 128 by construction
            }
        }

    __syncthreads();   // pool complete
    const unsigned n = s_cnt;

    // Lane-parallel exact rescue: lane owns codes {lane, lane+64, ...}.
    // s is bitwise identical to the validated shuffle rescue: same 4-dim
    // partial expressions (same fp-contract shape), same binary-tree add
    // order as the xor butterfly, same  p + nshc[c]  final add.
    for (unsigned e = wave; e < n; e += 4) {
        const unsigned row = __builtin_amdgcn_readfirstlane(s_rows[e]);
        const float4* xr = (const float4*)(inputs + (size_t)row * DIM);
        float4 x0 = xr[0], x1 = xr[1], x2 = xr[2], x3 = xr[3];
        float4 x4 = xr[4], x5 = xr[5], x6 = xr[6], x7 = xr[7];
        float4 x8 = xr[8], x9 = xr[9], x10 = xr[10], x11 = xr[11];
        float4 x12 = xr[12], x13 = xr[13], x14 = xr[14], x15 = xr[15];
        float rb = -INFINITY;
        int rbi = 0;
        for (int k = 0; k < 16; ++k) {
            const int c = k * 64 + lane;
            const float4* cr = (const float4*)(cb + (size_t)c * DIM);
            // first 8 chunks (8 independent loads in flight)
            float4 c0 = cr[0], c1 = cr[1], c2 = cr[2], c3 = cr[3];
            float4 c4_ = cr[4], c5 = cr[5], c6 = cr[6], c7 = cr[7];
            float q0 = DOT4(x0, c0), q1 = DOT4(x1, c1);
            float q2 = DOT4(x2, c2), q3 = DOT4(x3, c3);
            float q4 = DOT4(x4, c4_), q5 = DOT4(x5, c5);
            float q6 = DOT4(x6, c6), q7 = DOT4(x7, c7);
            float t0 = ((q0 + q1) + (q2 + q3)) + ((q4 + q5) + (q6 + q7));
            // second 8 chunks
            float4 d0 = cr[8], d1 = cr[9], d2 = cr[10], d3 = cr[11];
            float4 d4 = cr[12], d5 = cr[13], d6 = cr[14], d7 = cr[15];
            float r0 = DOT4(x8, d0), r1 = DOT4(x9, d1);
            float r2 = DOT4(x10, d2), r3 = DOT4(x11, d3);
            float r4 = DOT4(x12, d4), r5 = DOT4(x13, d5);
            float r6 = DOT4(x14, d6), r7 = DOT4(x15, d7);
            float t1 = ((r0 + r1) + (r2 + r3)) + ((r4 + r5) + (r6 + r7));
            float s = (t0 + t1) + nshc[c];
            if (s > rb) { rb = s; rbi = c; }   // per-lane ascending code order
        }
        // cross-lane top-1, min-index tie-break (validated pattern), 6 levels
#pragma unroll
        for (int off = 1; off < 64; off <<= 1) {
            float ob = __shfl_xor(rb, off);
            int oi = __shfl_xor(rbi, off);
            if (ob > rb || (ob == rb && oi < rbi)) { rb = ob; rbi = oi; }
        }
        out[(size_t)row * DIM + lane] = cb[(size_t)rbi * DIM + lane];
    }
}

extern "C" void kernel_launch(void* const* d_in, const int* in_sizes, int n_in,
                              void* d_out, int out_size, void* d_ws, size_t ws_size,
                              hipStream_t stream_) {
    const float* inputs = (const float*)d_in[0];    // [262144, 64] fp32
    const float* cb = (const float*)d_in[1];        // [1024, 64] fp32
    float* out = (float*)d_out;

    // ws: hcsq f32[1024] | tile stream [68 x 2048 B] | eslots f32[16]
    char* ws = (char*)d_ws;
    float* hcsq = (float*)ws;                                       //   4 KiB
    char* strm = ws + 4096;                                         // 136 KiB
    float* eslots = (float*)(ws + 4096 + (NTILES + PADT) * TILEB);

    vq_prep<<<4, 256, 0, stream_>>>(cb, hcsq, strm, eslots);
    vq_main<<<NROWS / 128, 256, 0, stream_>>>(inputs, cb, hcsq, strm, eslots, out);
}

// Round 13
// 246.939 us; speedup vs baseline: 1.4500x; 1.4500x over previous
//
#include <hip/hip_runtime.h>

#define NROWS   262144
#define NCODES  1024
#define DIM     64
#define NTILES  64       // 16-code MFMA tiles covering 1024 codes
#define TILEB   4096     // bytes per tile: [ch frags 2048][cl frags 2048]
#define PADT    4        // prefetch overrun pad (tiles 64..67 read, never used)

typedef _Float16 half8 __attribute__((ext_vector_type(8)));
typedef __attribute__((ext_vector_type(4))) float f32x4;

#define MFMA16(acc, a, b) acc = __builtin_amdgcn_mfma_f32_16x16x32_f16(a, b, acc, 0, 0, 0)

// ---------------------------------------------------------------------------
// Prep. Validated sequential s-chain and RNE fp16 kept. NEW (R13): two-level
// codebook quantization ch = fp16(c), cl = fp16(c - ch); both stored in the
// R3-validated fragment layout (cl region at tile_base + 2048). Three exact
// error scalars reduced per wave into eslots (plain stores, no atomics):
//   eslots[w]    = max ||c - ch - cl||^2   (E_r^2)
//   eslots[16+w] = max ||cl||^2            (E_cl^2)
//   eslots[32+w] = max ||c||^2             (Cmax^2)
// ---------------------------------------------------------------------------
__global__ __launch_bounds__(256) void vq_prep(const float* __restrict__ cb,
                                               float* __restrict__ hcsq,
                                               char* __restrict__ stream,
                                               float* __restrict__ eslots) {
    const int k = blockIdx.x * 256 + threadIdx.x;   // 0..1023
    const float4* row = (const float4*)(cb + (size_t)k * DIM);
    char* base = stream + (size_t)(k >> 4) * TILEB + (size_t)(k & 15) * 16;
    float s = 0.f, r2 = 0.f, cl2 = 0.f;
#pragma unroll
    for (int i = 0; i < 8; ++i) {   // chunk i: elements i*8..i*8+7
        float4 a = row[2 * i], b = row[2 * i + 1];
        float v[8] = {a.x, a.y, a.z, a.w, b.x, b.y, b.z, b.w};
        union { half8 f; _Float16 e[8]; } uh, ul;
#pragma unroll
        for (int j = 0; j < 8; ++j) {
            float c = v[j];
            s += c * c;                     // sequential chain (validated)
            _Float16 h = (_Float16)c;       // RNE
            float d1 = c - (float)h;
            _Float16 l = (_Float16)d1;      // RNE second level
            float d = d1 - (float)l;        // true 3-term residual
            uh.e[j] = h;
            ul.e[j] = l;
            r2 += d * d;
            cl2 += (float)l * (float)l;
        }
        const int off = ((i >> 2) << 10) + ((i & 3) << 8);   // validated layout
        *(half8*)(base + off) = uh.f;
        *(half8*)(base + 2048 + off) = ul.f;
    }
    hcsq[k] = 0.5f * s;
    float wr = r2, wc = cl2, wsq = s;
#pragma unroll
    for (int off = 1; off < 64; off <<= 1) {
        wr = fmaxf(wr, __shfl_xor(wr, off));
        wc = fmaxf(wc, __shfl_xor(wc, off));
        wsq = fmaxf(wsq, __shfl_xor(wsq, off));
    }
    if ((threadIdx.x & 63) == 0) {
        const int wid = blockIdx.x * 4 + (threadIdx.x >> 6);
        eslots[wid] = wr;
        eslots[16 + wid] = wc;
        eslots[32 + wid] = wsq;
    }
}

// ---------------------------------------------------------------------------
// Main. R3's loop structure with a third MFMA term (xh·cl): per tile 12 MFMA,
// 4 half8 frag loads (ch pair + cl pair), 4-deep rotating prefetch. Score
// S = xh·ch + xl·ch + xh·cl - 0.5||c||^2; missing terms bounded by ||x||·K,
//   K = 1.01*(E_r + 2^-10*E_cl + 2^-21*Cmax)   (~1e-5 vs old E ~4e-3)
// -> margin is dominated by the validated 1e-3 slack -> flags drop ~30x
// (~8000 -> ~270, lambda ~0.13/block). Flagged rows: block-pooled, then
// block-COOPERATIVE exact rescue -- each wave scans a 256-code quarter with
// the validated 16-lane dot + 4-level butterfly VERBATIM, then the 4
// (val,idx) candidates merge via LDS with the min-index tie-break (quarters
// are ascending disjoint ranges -> winner identical to the validated full
// scan). ~6 us/row instead of ~21, worst block ~3 rows.
// ---------------------------------------------------------------------------
#define SELECT(aa, ab, tl)                                                        \
    {                                                                             \
        const int _tl = (tl);                                                     \
        _Pragma("unroll")                                                         \
        for (int r = 0; r < 4; ++r) {                                             \
            float s0 = (aa)[r];                                                   \
            bool g0 = s0 > best[0][r];                                            \
            second[0][r] = __builtin_amdgcn_fmed3f(s0, best[0][r], second[0][r]); \
            best[0][r] = g0 ? s0 : best[0][r];                                    \
            btile[0][r] = g0 ? _tl : btile[0][r];                                 \
            float s1 = (ab)[r];                                                   \
            bool g1 = s1 > best[1][r];                                            \
            second[1][r] = __builtin_amdgcn_fmed3f(s1, best[1][r], second[1][r]); \
            best[1][r] = g1 ? s1 : best[1][r];                                    \
            btile[1][r] = g1 ? _tl : btile[1][r];                                 \
        }                                                                         \
    }

// One tile: lag-1 select of the other acc pair; acc init = -hc (LDS, covered
// by SELECT); 12 MFMA (2 independent 6-chains); refill 4 frags from tile T+4.
#define PHASE(fA, fB, gA, gB, a0, a1, o0, o1, TT)             \
    {                                                         \
        const int _T = (TT);                                  \
        float nh = nshc[_T * 16 + m];                         \
        SELECT(o0, o1, _T - 1);                               \
        a0 = (f32x4){nh, nh, nh, nh};                         \
        a1 = a0;                                              \
        MFMA16(a0, xh[0][0], fA); MFMA16(a1, xh[1][0], fA);   \
        MFMA16(a0, xh[0][1], fB); MFMA16(a1, xh[1][1], fB);   \
        MFMA16(a0, xl[0][0], fA); MFMA16(a1, xl[1][0], fA);   \
        MFMA16(a0, xl[0][1], fB); MFMA16(a1, xl[1][1], fB);   \
        MFMA16(a0, xh[0][0], gA); MFMA16(a1, xh[1][0], gA);   \
        MFMA16(a0, xh[0][1], gB); MFMA16(a1, xh[1][1], gB);   \
        fA = *(const half8*)(gpre);                           \
        fB = *(const half8*)(gpre + 1024);                    \
        gA = *(const half8*)(gpre + 2048);                    \
        gB = *(const half8*)(gpre + 3072);                    \
        gpre += TILEB;                                        \
    }

__global__ __launch_bounds__(256, 4) void vq_main(const float* __restrict__ inputs,
                                                  const float* __restrict__ cb,
                                                  const float* __restrict__ hcsq,
                                                  const char* __restrict__ stream,
                                                  const float* __restrict__ eslots,
                                                  float* __restrict__ out) {
    __shared__ float nshc[NCODES];     // negated 0.5||c||^2
    __shared__ unsigned s_rows[128];   // block-pooled flagged rows
    __shared__ unsigned s_cnt;
    __shared__ float s_cval[128 * 4];  // rescue candidates (val)
    __shared__ int s_cidx[128 * 4];    // rescue candidates (idx)
    const int tid = threadIdx.x;
    const int lane = tid & 63;
    const int wave = tid >> 6;
    const int m = lane & 15;   // A row-in-tile / B code-in-tile / D col
    const int q = lane >> 4;   // k-quad
    const size_t rowbase = (size_t)blockIdx.x * 128 + (size_t)wave * 32;

    for (int i = tid; i < NCODES; i += 256) nshc[i] = -hcsq[i];
    if (tid == 0) s_cnt = 0u;

    float r2m = 0.f, cl2m = 0.f, sm = 0.f;
#pragma unroll
    for (int i = 0; i < 16; ++i) {
        r2m = fmaxf(r2m, eslots[i]);
        cl2m = fmaxf(cl2m, eslots[16 + i]);
        sm = fmaxf(sm, eslots[32 + i]);
    }
    const float K = (sqrtf(r2m) + 0x1p-10f * sqrtf(cl2m) + 0x1p-21f * sqrtf(sm)) * 1.01f;

    // A fragments (fp16 hi+lo of x) + exact row sum-of-squares for the margin.
    half8 xh[2][2], xl[2][2];
    float xsq[2];
#pragma unroll
    for (int t = 0; t < 2; ++t) {
        const float* px = inputs + (rowbase + t * 16 + m) * DIM;
        float acc = 0.f;
#pragma unroll
        for (int s = 0; s < 2; ++s) {
            const float4* p = (const float4*)(px + q * 8 + s * 32);
            float4 v0 = p[0], v1 = p[1];
            float v[8] = {v0.x, v0.y, v0.z, v0.w, v1.x, v1.y, v1.z, v1.w};
            union { half8 f; _Float16 e[8]; } uh, ul;
#pragma unroll
            for (int j = 0; j < 8; ++j) {
                acc += v[j] * v[j];
                _Float16 h = (_Float16)v[j];
                uh.e[j] = h;
                ul.e[j] = (_Float16)(v[j] - (float)h);
            }
            xh[t][s] = uh.f;
            xl[t][s] = ul.f;
        }
        acc += __shfl_xor(acc, 16);   // reduce across k-quads (same m)
        acc += __shfl_xor(acc, 32);
        xsq[t] = acc;
    }
    __syncthreads();   // nshc + s_cnt ready

    float best[2][4], second[2][4];
    int btile[2][4];
#pragma unroll
    for (int t = 0; t < 2; ++t)
#pragma unroll
        for (int r = 0; r < 4; ++r) {
            best[t][r] = -INFINITY;
            second[t][r] = -INFINITY;
            btile[t][r] = 0;
        }

    // 4-deep rotating prefetch: 4 half8 per tile slot (ch pair + cl pair).
    const char* gL = stream + (size_t)lane * 16;
    half8 f0a = *(const half8*)(gL);
    half8 f0b = *(const half8*)(gL + 1024);
    half8 g0a = *(const half8*)(gL + 2048);
    half8 g0b = *(const half8*)(gL + 3072);
    half8 f1a = *(const half8*)(gL + TILEB);
    half8 f1b = *(const half8*)(gL + TILEB + 1024);
    half8 g1a = *(const half8*)(gL + TILEB + 2048);
    half8 g1b = *(const half8*)(gL + TILEB + 3072);
    half8 f2a = *(const half8*)(gL + 2 * TILEB);
    half8 f2b = *(const half8*)(gL + 2 * TILEB + 1024);
    half8 g2a = *(const half8*)(gL + 2 * TILEB + 2048);
    half8 g2b = *(const half8*)(gL + 2 * TILEB + 3072);
    half8 f3a = *(const half8*)(gL + 3 * TILEB);
    half8 f3b = *(const half8*)(gL + 3 * TILEB + 1024);
    half8 g3a = *(const half8*)(gL + 3 * TILEB + 2048);
    half8 g3b = *(const half8*)(gL + 3 * TILEB + 3072);
    const char* gpre = gL + 4 * TILEB;

    f32x4 accA0, accA1, accB0, accB1;
    accB0 = (f32x4){-INFINITY, -INFINITY, -INFINITY, -INFINITY};
    accB1 = accB0;

    for (int it = 0; it < 16; ++it) {
        const int T = it * 4;
        PHASE(f0a, f0b, g0a, g0b, accA0, accA1, accB0, accB1, T + 0);
        PHASE(f1a, f1b, g1a, g1b, accB0, accB1, accA0, accA1, T + 1);
        PHASE(f2a, f2b, g2a, g2b, accA0, accA1, accB0, accB1, T + 2);
        PHASE(f3a, f3b, g3a, g3b, accB0, accB1, accA0, accA1, T + 3);
    }
    SELECT(accB0, accB1, NTILES - 1);   // drain last pending tile

    // Top-2 merge; write non-flagged rows; pool flagged rows in LDS (R9 fix).
#pragma unroll
    for (int t = 0; t < 2; ++t)
#pragma unroll
        for (int r = 0; r < 4; ++r) {
            float b = best[t][r], sc = second[t][r];
            int bi = btile[t][r] * 16 + m;   // reconstruct code index
#pragma unroll
            for (int off = 1; off < 16; off <<= 1) {
                float ob = __shfl_xor(b, off);
                float os = __shfl_xor(sc, off);
                int oi = __shfl_xor(bi, off);
                sc = fmaxf(fmaxf(sc, os), fminf(b, ob));
                if (ob > b || (ob == b && oi < bi)) { b = ob; bi = oi; }
            }
            size_t row = rowbase + t * 16 + q * 4 + r;
            float xs = __shfl(xsq[t], (lane & 48) | (q * 4 + r));
            float marg = 2.0f * (sqrtf(xs) * K + 1e-3f);
            bool flg = (b - sc) < marg;   // group-uniform
            if (!flg) {
                const float4* src = (const float4*)(cb + (size_t)bi * DIM);
                ((float4*)(out + row * DIM))[m] = src[m];
            } else if (m == 0) {
                unsigned p = atomicAdd(&s_cnt, 1u);   // LDS atomic
                s_rows[p] = (unsigned)row;            // p < 128 by construction
            }
        }

    __syncthreads();   // pool complete
    const unsigned n = s_cnt;

    // Block-cooperative exact rescue. Phase 1 (no barrier inside): for each
    // flagged row, wave w scans codes [w*256, w*256+256) with the validated
    // 16-lane dot + 4-level butterfly + (16,32) merge, writes its (val,idx).
    const int sub = lane & 15;  // dim quad
    const int g = lane >> 4;    // code within 4-group
    for (unsigned e = 0; e < n; ++e) {
        const size_t row = s_rows[e];
        float4 xv = ((const float4*)(inputs + row * DIM))[sub];
        float rb = -INFINITY;
        int rbi = 0;
#pragma unroll 8
        for (int c4 = 0; c4 < 64; ++c4) {
            int c = wave * 256 + c4 * 4 + g;
            float4 cv = ((const float4*)(cb + (size_t)c * DIM))[sub];
            float p = xv.x * cv.x + xv.y * cv.y + xv.z * cv.z + xv.w * cv.w;
            p += __shfl_xor(p, 1);
            p += __shfl_xor(p, 2);
            p += __shfl_xor(p, 4);
            p += __shfl_xor(p, 8);
            float s = p + nshc[c];   // == p - hcsq[c] (negation exact)
            if (s > rb) { rb = s; rbi = c; }
        }
#pragma unroll
        for (int off = 16; off < 64; off <<= 1) {
            float ob = __shfl_xor(rb, off);
            int oi = __shfl_xor(rbi, off);
            if (ob > rb || (ob == rb && oi < rbi)) { rb = ob; rbi = oi; }
        }
        if (lane == 0) {
            s_cval[e * 4 + wave] = rb;
            s_cidx[e * 4 + wave] = rbi;
        }
    }
    __syncthreads();   // candidates complete

    // Phase 2: row e merged+written by wave e&3 (quarters ascending ->
    // min-index tie-break gives the exact validated winner).
    for (unsigned e = wave; e < n; e += 4) {
        const size_t row = s_rows[e];
        float bv = s_cval[e * 4];
        int bi2 = s_cidx[e * 4];
#pragma unroll
        for (int w = 1; w < 4; ++w) {
            float v = s_cval[e * 4 + w];
            int i2 = s_cidx[e * 4 + w];
            if (v > bv || (v == bv && i2 < bi2)) { bv = v; bi2 = i2; }
        }
        out[row * DIM + lane] = cb[(size_t)bi2 * DIM + lane];
    }
}

extern "C" void kernel_launch(void* const* d_in, const int* in_sizes, int n_in,
                              void* d_out, int out_size, void* d_ws, size_t ws_size,
                              hipStream_t stream_) {
    const float* inputs = (const float*)d_in[0];    // [262144, 64] fp32
    const float* cb = (const float*)d_in[1];        // [1024, 64] fp32
    float* out = (float*)d_out;

    // ws: hcsq f32[1024] | tile stream [68 x 4096 B] | eslots f32[48]
    char* ws = (char*)d_ws;
    float* hcsq = (float*)ws;                                       //   4 KiB
    char* strm = ws + 4096;                                         // 272 KiB
    float* eslots = (float*)(ws + 4096 + (NTILES + PADT) * TILEB);

    vq_prep<<<4, 256, 0, stream_>>>(cb, hcsq, strm, eslots);
    vq_main<<<NROWS / 128, 256, 0, stream_>>>(inputs, cb, hcsq, strm, eslots, out);
}